// Round 4
// baseline (481.594 us; speedup 1.0000x reference)
//
#include <hip/hip_runtime.h>

// Nearest-qpoint quantize, bit-exact vs the numpy reference:
//   idx = searchsorted(q, x); lo = q[clip(idx-1,0,15)]; hi = q[clip(idx,0,15)]
//   out = |x-lo| <= |x-hi| ? lo : hi
//
// R5: single fused kernel.
//  - Thresholds t_k = max{x : |x-q[k]| <= |x-q[k+1]|} are bisected IN-KERNEL,
//    once per wave: lane k<15 bisects pair k in ordered-bit space using the
//    reference's own fp32 predicate (monotone non-increasing in x), then
//    v_readlane broadcasts each to SGPRs. Bit-exact incl. ties; no setup
//    launch, no workspace, no t-table VMEM loads (R3 paid ~6us for those).
//  - Main loop processes TWO float4 per iteration with both loads issued
//    before any compute: 2 outstanding VMEM/wave instead of 1. R1/R3 measured
//    ~4.97 TB/s vs the 6.29 TB/s float4-copy ceiling (m13); the single
//    in-flight load per wave is the suspected limiter.
//  - 15-compare thermometer chain (30 VALU ops/elem) is retained: VALU issue
//    stays far below the memory floor (~26us vs ~90us).

typedef float f32x4 __attribute__((ext_vector_type(4)));

__device__ __forceinline__ float rfl(float v) {
    return __int_as_float(__builtin_amdgcn_readfirstlane(__float_as_int(v)));
}
__device__ __forceinline__ float rdlane(float v, int lane) {
    return __int_as_float(__builtin_amdgcn_readlane(__float_as_int(v), lane));
}

// Monotone float <-> ordered-uint bijection (finite values; qpoints are in
// [-1.5, 1.5] so this is total on the domain we bisect).
__device__ __forceinline__ unsigned f2o(float f) {
    unsigned b = __float_as_uint(f);
    return (b & 0x80000000u) ? ~b : (b | 0x80000000u);
}
__device__ __forceinline__ float o2f(unsigned o) {
    unsigned b = (o & 0x80000000u) ? (o ^ 0x80000000u) : ~o;
    return __uint_as_float(b);
}

__device__ __forceinline__ float chain16(float xv, const float qp[16],
                                         const float th[15]) {
    float r = qp[0];
#pragma unroll
    for (int k = 0; k < 15; ++k) r = (xv > th[k]) ? qp[k + 1] : r;
    return r;
}

__global__ __launch_bounds__(256) void qquant_fused(
    const f32x4* __restrict__ x, const float* __restrict__ q,
    f32x4* __restrict__ out, int n2) {
    // qpoints -> SGPRs (wave-uniform vector loads + readfirstlane).
    const f32x4* q4 = (const f32x4*)q;
    f32x4 qa = q4[0], qb = q4[1], qc = q4[2], qd = q4[3];
    float qp[16] = {rfl(qa.x), rfl(qa.y), rfl(qa.z), rfl(qa.w),
                    rfl(qb.x), rfl(qb.y), rfl(qb.z), rfl(qb.w),
                    rfl(qc.x), rfl(qc.y), rfl(qc.z), rfl(qc.w),
                    rfl(qd.x), rfl(qd.y), rfl(qd.z), rfl(qd.w)};

    // Per-wave threshold bisection. Lane k<15 owns pair (q[k], q[k+1]).
    // Divergent while loop is exec-masked, <=31 iterations, once per wave.
    int lane = threadIdx.x & 63;
    float tval = 0.0f;
    if (lane < 15) {
        float lo = q[lane], hi = q[lane + 1];   // per-lane scalar loads, L2-hit
        unsigned a = f2o(lo), b = f2o(hi);
        while (b - a > 1u) {
            unsigned m = a + ((b - a) >> 1);
            float xm = o2f(m);
            if (fabsf(xm - lo) <= fabsf(xm - hi)) a = m; else b = m;
        }
        tval = o2f(a);
    }
    float th[15];
#pragma unroll
    for (int j = 0; j < 15; ++j) th[j] = rdlane(tval, j);  // SGPR broadcast

    // Grid-stride over PAIRS of float4: both loads in flight before compute.
    int stride = gridDim.x * blockDim.x;
    for (int p = blockIdx.x * blockDim.x + threadIdx.x; p < n2; p += stride) {
        const f32x4* src = &x[2 * p];
        f32x4 v0 = __builtin_nontemporal_load(&src[0]);
        f32x4 v1 = __builtin_nontemporal_load(&src[1]);
        f32x4 r0, r1;
        r0.x = chain16(v0.x, qp, th);
        r0.y = chain16(v0.y, qp, th);
        r0.z = chain16(v0.z, qp, th);
        r0.w = chain16(v0.w, qp, th);
        r1.x = chain16(v1.x, qp, th);
        r1.y = chain16(v1.y, qp, th);
        r1.z = chain16(v1.z, qp, th);
        r1.w = chain16(v1.w, qp, th);
        f32x4* dst = &out[2 * p];
        __builtin_nontemporal_store(r0, &dst[0]);
        __builtin_nontemporal_store(r1, &dst[1]);
    }
}

// Tail: covers the (n - n2*8) < 8 leftover scalar elements.
__device__ __forceinline__ float quant1(float xv, const float qp[16]) {
    float hi = qp[15];
#pragma unroll
    for (int k = 14; k >= 0; --k) hi = (qp[k] >= xv) ? qp[k] : hi;
    float lo = qp[0];
#pragma unroll
    for (int k = 1; k < 16; ++k) lo = (qp[k] < xv) ? qp[k] : lo;
    return (fabsf(xv - lo) <= fabsf(xv - hi)) ? lo : hi;
}

__global__ void qquant_tail(const float* __restrict__ x,
                            const float* __restrict__ q,
                            float* __restrict__ out, int start, int n) {
    int i = start + threadIdx.x;
    if (i >= n) return;
    float qp[16];
#pragma unroll
    for (int k = 0; k < 16; ++k) qp[k] = q[k];
    out[i] = quant1(x[i], qp);
}

extern "C" void kernel_launch(void* const* d_in, const int* in_sizes, int n_in,
                              void* d_out, int out_size, void* d_ws, size_t ws_size,
                              hipStream_t stream) {
    const float* x = (const float*)d_in[0];
    const float* q = (const float*)d_in[1];
    float* out = (float*)d_out;
    int n = in_sizes[0];

    int n2 = n >> 3;  // pairs of float4 (8 elements each)
    if (n2 > 0) {
        int blocks = (n2 + 255) / 256;
        if (blocks > 8192) blocks = 8192;
        qquant_fused<<<blocks, 256, 0, stream>>>((const f32x4*)x, q,
                                                 (f32x4*)out, n2);
    }
    int done = n2 << 3;
    if (n - done > 0) {  // host-side branch on constant sizes: capture-safe
        qquant_tail<<<1, 64, 0, stream>>>(x, q, out, done, n);
    }
}

// Round 5
// 424.487 us; speedup vs baseline: 1.1345x; 1.1345x over previous
//
#include <hip/hip_runtime.h>

// Nearest-qpoint quantize, bit-exact vs the numpy reference:
//   idx = searchsorted(q, x); lo = q[clip(idx-1,0,15)]; hi = q[clip(idx,0,15)]
//   out = |x-lo| <= |x-hi| ? lo : hi
//
// R6: fix R5's regression. rocprof showed LDS_Block_Size=16384 + 9.75M bank
// conflicts on a kernel with no __shared__: AMDGPUPromoteAlloca moved qp[16]
// into LDS (the divergent bisection blocked mem2reg scalarization of the
// array). Every compare became a strided ds_read -> 3.3 TB/s. Fix: NO private
// arrays at all -- qp0..qp15 / th0..th14 are named scalars (SGPRs), the
// compare chain is a macro with constant references.
// Also: R5's pair layout (2p, 2p+1) made per-lane accesses 32B-strided
// (WRITE_SIZE 399MB for a 268MB output). R6 loads x[i] and x[i+stride]:
// both 16B/lane fully coalesced, still 2 VMEM in flight per wave.
//
// Thresholds t_k = max{x : |x-q[k]| <= |x-q[k+1]|} are bisected in-kernel
// once per wave (lane k<15, exec-masked, <=31 iters) using the reference's
// own fp32 predicate -> bit-exact incl. ties; readlane broadcasts to SGPRs.

typedef float f32x4 __attribute__((ext_vector_type(4)));

__device__ __forceinline__ float rfl(float v) {
    return __int_as_float(__builtin_amdgcn_readfirstlane(__float_as_int(v)));
}
__device__ __forceinline__ float rdlane(float v, int lane) {
    return __int_as_float(__builtin_amdgcn_readlane(__float_as_int(v), lane));
}

// Monotone float <-> ordered-uint bijection (finite values; qpoints are in
// [-1.5, 1.5] so this is total on the domain we bisect).
__device__ __forceinline__ unsigned f2o(float f) {
    unsigned b = __float_as_uint(f);
    return (b & 0x80000000u) ? ~b : (b | 0x80000000u);
}
__device__ __forceinline__ float o2f(unsigned o) {
    unsigned b = (o & 0x80000000u) ? (o ^ 0x80000000u) : ~o;
    return __uint_as_float(b);
}

// 15-compare thermometer chain over named scalars in enclosing scope.
#define CHAIN16(xv) ({                         \
    float r_ = qp0;                            \
    r_ = ((xv) > th0)  ? qp1  : r_;            \
    r_ = ((xv) > th1)  ? qp2  : r_;            \
    r_ = ((xv) > th2)  ? qp3  : r_;            \
    r_ = ((xv) > th3)  ? qp4  : r_;            \
    r_ = ((xv) > th4)  ? qp5  : r_;            \
    r_ = ((xv) > th5)  ? qp6  : r_;            \
    r_ = ((xv) > th6)  ? qp7  : r_;            \
    r_ = ((xv) > th7)  ? qp8  : r_;            \
    r_ = ((xv) > th8)  ? qp9  : r_;            \
    r_ = ((xv) > th9)  ? qp10 : r_;            \
    r_ = ((xv) > th10) ? qp11 : r_;            \
    r_ = ((xv) > th11) ? qp12 : r_;            \
    r_ = ((xv) > th12) ? qp13 : r_;            \
    r_ = ((xv) > th13) ? qp14 : r_;            \
    r_ = ((xv) > th14) ? qp15 : r_;            \
    r_; })

__global__ __launch_bounds__(256) void qquant_fused(
    const f32x4* __restrict__ x, const float* __restrict__ q,
    f32x4* __restrict__ out, int n4) {
    // qpoints -> named SGPR scalars (wave-uniform vector loads + readfirstlane).
    const f32x4* q4 = (const f32x4*)q;
    f32x4 qa = q4[0], qb = q4[1], qc = q4[2], qd = q4[3];
    float qp0 = rfl(qa.x), qp1 = rfl(qa.y), qp2 = rfl(qa.z), qp3 = rfl(qa.w);
    float qp4 = rfl(qb.x), qp5 = rfl(qb.y), qp6 = rfl(qb.z), qp7 = rfl(qb.w);
    float qp8 = rfl(qc.x), qp9 = rfl(qc.y), qp10 = rfl(qc.z), qp11 = rfl(qc.w);
    float qp12 = rfl(qd.x), qp13 = rfl(qd.y), qp14 = rfl(qd.z), qp15 = rfl(qd.w);

    // Per-wave threshold bisection: lane k<15 owns pair (q[k], q[k+1]).
    int lane = threadIdx.x & 63;
    float tval = 0.0f;
    if (lane < 15) {
        float lo = q[lane], hi = q[lane + 1];   // tiny divergent loads, L2-hit
        unsigned a = f2o(lo), b = f2o(hi);
        while (b - a > 1u) {
            unsigned m = a + ((b - a) >> 1);
            float xm = o2f(m);
            if (fabsf(xm - lo) <= fabsf(xm - hi)) a = m; else b = m;
        }
        tval = o2f(a);
    }
    float th0 = rdlane(tval, 0), th1 = rdlane(tval, 1), th2 = rdlane(tval, 2);
    float th3 = rdlane(tval, 3), th4 = rdlane(tval, 4), th5 = rdlane(tval, 5);
    float th6 = rdlane(tval, 6), th7 = rdlane(tval, 7), th8 = rdlane(tval, 8);
    float th9 = rdlane(tval, 9), th10 = rdlane(tval, 10);
    float th11 = rdlane(tval, 11), th12 = rdlane(tval, 12);
    float th13 = rdlane(tval, 13), th14 = rdlane(tval, 14);

    // Grid-stride, 2 fully-coalesced float4 loads in flight per iteration.
    int stride = gridDim.x * blockDim.x;
    int i = blockIdx.x * blockDim.x + threadIdx.x;
    for (; i + stride < n4; i += 2 * stride) {
        f32x4 v0 = __builtin_nontemporal_load(&x[i]);
        f32x4 v1 = __builtin_nontemporal_load(&x[i + stride]);
        f32x4 r0, r1;
        r0.x = CHAIN16(v0.x);
        r0.y = CHAIN16(v0.y);
        r0.z = CHAIN16(v0.z);
        r0.w = CHAIN16(v0.w);
        r1.x = CHAIN16(v1.x);
        r1.y = CHAIN16(v1.y);
        r1.z = CHAIN16(v1.z);
        r1.w = CHAIN16(v1.w);
        __builtin_nontemporal_store(r0, &out[i]);
        __builtin_nontemporal_store(r1, &out[i + stride]);
    }
    if (i < n4) {
        f32x4 v0 = __builtin_nontemporal_load(&x[i]);
        f32x4 r0;
        r0.x = CHAIN16(v0.x);
        r0.y = CHAIN16(v0.y);
        r0.z = CHAIN16(v0.z);
        r0.w = CHAIN16(v0.w);
        __builtin_nontemporal_store(r0, &out[i]);
    }
}

// Tail: covers the (n & 3) leftover scalar elements (never launches for the
// bench shape n = 64M; kept for generality).
__global__ void qquant_tail(const float* __restrict__ x,
                            const float* __restrict__ q,
                            float* __restrict__ out, int start, int n) {
    int i = start + threadIdx.x;
    if (i >= n) return;
    float xv = x[i];
    float hi = q[15];
#pragma unroll
    for (int k = 14; k >= 0; --k) { float qk = q[k]; hi = (qk >= xv) ? qk : hi; }
    float lo = q[0];
#pragma unroll
    for (int k = 1; k < 16; ++k) { float qk = q[k]; lo = (qk < xv) ? qk : lo; }
    out[i] = (fabsf(xv - lo) <= fabsf(xv - hi)) ? lo : hi;
}

extern "C" void kernel_launch(void* const* d_in, const int* in_sizes, int n_in,
                              void* d_out, int out_size, void* d_ws, size_t ws_size,
                              hipStream_t stream) {
    const float* x = (const float*)d_in[0];
    const float* q = (const float*)d_in[1];
    float* out = (float*)d_out;
    int n = in_sizes[0];

    int n4 = n >> 2;
    if (n4 > 0) {
        int blocks = (n4 + 255) / 256;
        if (blocks > 8192) blocks = 8192;
        qquant_fused<<<blocks, 256, 0, stream>>>((const f32x4*)x, q,
                                                 (f32x4*)out, n4);
    }
    int done = n4 << 2;
    if (n - done > 0) {  // host-side branch on constant sizes: capture-safe
        qquant_tail<<<1, 64, 0, stream>>>(x, q, out, done, n);
    }
}